// Round 1
// baseline (410.588 us; speedup 1.0000x reference)
//
#include <hip/hip_runtime.h>

// N=100000 nodes, M=800000 edges, F_IN=64, F_E=16, H=64, T_NODE=2, T_EDGE=3.
// score == softmax over singleton axis == 1.0 exactly, so h3/h4/num are dead:
//   out[n] = h1[n] + sum_{e: dst=n} ( h2[src_e] + ef_e . W5[t_e] + b5[t_e] )

#define EPW 32  // edges per wave in edge kernel

__device__ __forceinline__ void fma4(float4& a, float s, const float4& w) {
    a.x = fmaf(s, w.x, a.x);
    a.y = fmaf(s, w.y, a.y);
    a.z = fmaf(s, w.z, a.z);
    a.w = fmaf(s, w.w, a.w);
}

// ---------------- bucket nodes by type (2 types) ----------------
// type 0 takes positions [0, c0) from the front, type 1 takves [N-c1, N) from the back.
__global__ __launch_bounds__(256) void bucket_kernel(
    const int* __restrict__ node_type, int* __restrict__ perm,
    int* __restrict__ cnt, int N)
{
    int tid = blockIdx.x * 256 + threadIdx.x;
    if (tid >= N) return;
    int t = node_type[tid];
    unsigned long long m0 = __ballot(t == 0);
    unsigned long long m1 = __ballot(t != 0);
    int lane = threadIdx.x & 63;
    unsigned long long lt = (lane == 0) ? 0ull : ((~0ull) >> (64 - lane));
    if (t == 0) {
        int cntw = __popcll(m0);
        int pre  = __popcll(m0 & lt);
        int ldr  = __ffsll((unsigned long long)m0) - 1;
        int base = 0;
        if (lane == ldr) base = atomicAdd(&cnt[0], cntw);
        base = __shfl(base, ldr);
        perm[base + pre] = tid;
    } else {
        int cntw = __popcll(m1);
        int pre  = __popcll(m1 & lt);
        int ldr  = __ffsll((unsigned long long)m1) - 1;
        int base = 0;
        if (lane == ldr) base = atomicAdd(&cnt[1], cntw);
        base = __shfl(base, ldr);
        perm[N - 1 - (base + pre)] = tid;
    }
}

// ---------------- node projection: h1 -> out, h2 -> ws ----------------
// Tile: 128 rows x 64 cols. Block = 256 threads, thread = (ng: 8 nodes, hg: 4 h).
// All rows in a tile share one node type (thanks to bucketing), so W is uniform.
__global__ __launch_bounds__(256) void node_gemm_kernel(
    const float* __restrict__ x, const int* __restrict__ perm,
    const int* __restrict__ cnt,
    const float* __restrict__ W1, const float* __restrict__ b1,
    const float* __restrict__ W2, const float* __restrict__ b2,
    float* __restrict__ out, float* __restrict__ h2,
    int N, int nb)
{
    __shared__ float sx[64][128];   // [f][row] transposed x tile, 32 KB
    __shared__ float sW1[64][64];   // [f][h] 16 KB
    __shared__ float sW2[64][64];   // 16 KB

    int tid = threadIdx.x;
    int c0 = cnt[0];
    int side = (blockIdx.x >= (unsigned)nb) ? 1 : 0;
    int b = blockIdx.x - side * nb;
    int rowbase = side ? (c0 + b * 128) : (b * 128);
    int rowend  = side ? N : c0;
    if (rowbase >= rowend) return;

    const float* W1t = W1 + side * 4096;
    const float* W2t = W2 + side * 4096;
#pragma unroll
    for (int k = 0; k < 4; ++k) {
        int idx = k * 1024 + tid * 4;
        *(float4*)&sW1[0][idx] = *(const float4*)&W1t[idx];
        *(float4*)&sW2[0][idx] = *(const float4*)&W2t[idx];
    }

    // load x tile (transposed store)
    int fr = (tid & 15) * 4;
    int ir = tid >> 4;
#pragma unroll
    for (int it = 0; it < 8; ++it) {
        int i = it * 16 + ir;
        int r = rowbase + i;
        float4 v = make_float4(0.f, 0.f, 0.f, 0.f);
        if (r < rowend) {
            int n = perm[r];
            v = *(const float4*)&x[n * 64 + fr];
        }
        sx[fr + 0][i] = v.x;
        sx[fr + 1][i] = v.y;
        sx[fr + 2][i] = v.z;
        sx[fr + 3][i] = v.w;
    }
    __syncthreads();

    int hg = tid & 15;   // h quad: h = hg*4 + 0..3
    int ng = tid >> 4;   // node octet: rows ng*8 + 0..7
    float4 a1[8], a2[8];
#pragma unroll
    for (int j = 0; j < 8; ++j) {
        a1[j] = make_float4(0.f, 0.f, 0.f, 0.f);
        a2[j] = make_float4(0.f, 0.f, 0.f, 0.f);
    }

#pragma unroll 4
    for (int f = 0; f < 64; ++f) {
        float4 w1 = *(const float4*)&sW1[f][hg * 4];
        float4 w2 = *(const float4*)&sW2[f][hg * 4];
        float4 xa = *(const float4*)&sx[f][ng * 8];
        float4 xb = *(const float4*)&sx[f][ng * 8 + 4];
        fma4(a1[0], xa.x, w1); fma4(a2[0], xa.x, w2);
        fma4(a1[1], xa.y, w1); fma4(a2[1], xa.y, w2);
        fma4(a1[2], xa.z, w1); fma4(a2[2], xa.z, w2);
        fma4(a1[3], xa.w, w1); fma4(a2[3], xa.w, w2);
        fma4(a1[4], xb.x, w1); fma4(a2[4], xb.x, w2);
        fma4(a1[5], xb.y, w1); fma4(a2[5], xb.y, w2);
        fma4(a1[6], xb.z, w1); fma4(a2[6], xb.z, w2);
        fma4(a1[7], xb.w, w1); fma4(a2[7], xb.w, w2);
    }

    float4 bb1 = *(const float4*)&b1[side * 64 + hg * 4];
    float4 bb2 = *(const float4*)&b2[side * 64 + hg * 4];
#pragma unroll
    for (int j = 0; j < 8; ++j) {
        int r = rowbase + ng * 8 + j;
        if (r < rowend) {
            int n = perm[r];
            float4 o1 = make_float4(a1[j].x + bb1.x, a1[j].y + bb1.y,
                                    a1[j].z + bb1.z, a1[j].w + bb1.w);
            float4 o2 = make_float4(a2[j].x + bb2.x, a2[j].y + bb2.y,
                                    a2[j].z + bb2.z, a2[j].w + bb2.w);
            *(float4*)&out[n * 64 + hg * 4] = o1;
            *(float4*)&h2[n * 64 + hg * 4] = o2;
        }
    }
}

// ---------------- edge kernel ----------------
// One wave handles EPW consecutive edges; lane = h (0..63).
// W5/b5 live in registers (48+3 VGPRs), type selected by wave-uniform branch.
#define DOT16(W, B) ({                                              \
    float _s0 = (B), _s1 = 0.f;                                     \
    _Pragma("unroll")                                               \
    for (int _f = 0; _f < 16; _f += 2) {                            \
        _s0 = fmaf(efv[_f], W[_f], _s0);                            \
        _s1 = fmaf(efv[_f + 1], W[_f + 1], _s1);                    \
    }                                                               \
    _s0 + _s1; })

__global__ __launch_bounds__(256) void edge_kernel(
    const float* __restrict__ edge_feat,
    const int* __restrict__ esrc, const int* __restrict__ edst,
    const int* __restrict__ etype,
    const float* __restrict__ W5, const float* __restrict__ b5,
    const float* __restrict__ h2, float* __restrict__ out, int M)
{
    int lane = threadIdx.x & 63;
    int wid = __builtin_amdgcn_readfirstlane(threadIdx.x >> 6);
    int ebase = (blockIdx.x * 4 + wid) * EPW;
    if (ebase >= M) return;

    float w50[16], w51[16], w52[16];
#pragma unroll
    for (int f = 0; f < 16; ++f) {
        w50[f] = W5[f * 64 + lane];
        w51[f] = W5[1024 + f * 64 + lane];
        w52[f] = W5[2048 + f * 64 + lane];
    }
    float b50 = b5[lane], b51 = b5[64 + lane], b52 = b5[128 + lane];

    for (int i = 0; i < EPW; ++i) {
        int e = ebase + i;
        if (e >= M) break;                       // wave-uniform
        int s  = esrc[e];
        int d  = edst[e];
        int tt = etype[e];
        const float* efp = edge_feat + e * 16;   // uniform address -> s_load
        float efv[16];
#pragma unroll
        for (int f = 0; f < 16; ++f) efv[f] = efp[f];

        float acc;
        if (tt == 0)      acc = DOT16(w50, b50);
        else if (tt == 1) acc = DOT16(w51, b51);
        else              acc = DOT16(w52, b52);

        float msg = acc + h2[s * 64 + lane];
        unsafeAtomicAdd(&out[d * 64 + lane], msg);  // global_atomic_add_f32
    }
}

extern "C" void kernel_launch(void* const* d_in, const int* in_sizes, int n_in,
                              void* d_out, int out_size, void* d_ws, size_t ws_size,
                              hipStream_t stream) {
    const float* x  = (const float*)d_in[0];
    const float* ef = (const float*)d_in[1];
    const int* nt   = (const int*)d_in[2];
    const int* es   = (const int*)d_in[3];
    const int* ed   = (const int*)d_in[4];
    const int* et   = (const int*)d_in[5];
    const float* W1 = (const float*)d_in[6];
    const float* b1 = (const float*)d_in[7];
    const float* W2 = (const float*)d_in[8];
    const float* b2 = (const float*)d_in[9];
    // d_in[10..13] = W3,b3,W4,b4 are dead (score == 1.0)
    const float* W5 = (const float*)d_in[14];
    const float* b5 = (const float*)d_in[15];

    int N = in_sizes[2];
    int M = in_sizes[3];

    float* h2  = (float*)d_ws;
    int* perm  = (int*)((char*)d_ws + (size_t)N * 64 * 4);
    int* cnt   = perm + N;
    float* out = (float*)d_out;

    hipMemsetAsync(cnt, 0, 2 * sizeof(int), stream);

    int gb_bucket = (N + 255) / 256;
    bucket_kernel<<<gb_bucket, 256, 0, stream>>>(nt, perm, cnt, N);

    int nb = (N + 127) / 128;
    node_gemm_kernel<<<2 * nb, 256, 0, stream>>>(x, perm, cnt, W1, b1, W2, b2,
                                                 out, h2, N, nb);

    int gb_edge = (M + 4 * EPW - 1) / (4 * EPW);
    edge_kernel<<<gb_edge, 256, 0, stream>>>(ef, es, ed, et, W5, b5, h2, out, M);
}